// Round 8
// baseline (468.424 us; speedup 1.0000x reference)
//
#include <hip/hip_runtime.h>

// ---------------------------------------------------------------------------
// HAN link-prediction forward. fp16 MFMA GEMMs + fp16 intermediates,
// fp32 alpha tables / accumulation / output.
//   - _group with one metapath == identity (k*W/k*b/q* are dead params)
//   - concatenated 2N-segment CSR (one build serves both directions+layers)
//   - degree-bucketed node order: nodes sharing a wave have equal in-degree
//   - single-pass agg (alpha bounded -> exp without max-shift is exact),
//     4x-unrolled inner loop for memory-level parallelism
//   - GEMM: v_mfma_f32_16x16x32_f16, 32 rows/wave, ALL loads register-hoisted
//     (high VGPR by design: ILP > TLP for latency hiding), fused alpha epilogue
// ---------------------------------------------------------------------------

#define HEADS 4

typedef _Float16 f16x8 __attribute__((ext_vector_type(8)));
typedef _Float16 f16x4 __attribute__((ext_vector_type(4)));
typedef float    f32x4 __attribute__((ext_vector_type(4)));

__device__ __forceinline__ float leaky02(float a) {
    return a >= 0.f ? a : 0.2f * a;
}

// ---------------------------------------------------------------------------
// W prep: fp32 [K=128][M] row-major -> fp16 fragment-ordered
// ---------------------------------------------------------------------------
__device__ __forceinline__ void prep_one(const float* W, _Float16* Wf, int M, int o) {
    const int NT = M / 16;
    const int v = o & 7, lane = (o >> 3) & 63, jt = o >> 9;
    const int t = jt / NT, j = jt % NT;
    const int k = t * 32 + (lane >> 4) * 8 + v;
    const int n = j * 16 + (lane & 15);
    Wf[o] = (_Float16)W[k * M + n];
}

__global__ __launch_bounds__(256) void prep_w4(
    const float* __restrict__ W1, _Float16* __restrict__ Wf1,
    const float* __restrict__ W2, _Float16* __restrict__ Wf2,
    const float* __restrict__ W3, _Float16* __restrict__ Wf3,
    const float* __restrict__ W4, _Float16* __restrict__ Wf4) {
    int o = blockIdx.x * 256 + threadIdx.x;
    if (o < 16384)       prep_one(W1, Wf1, 128, o);
    else if (o < 32768)  prep_one(W2, Wf2, 128, o - 16384);
    else if (o < 40960)  prep_one(W3, Wf3, 64, o - 32768);
    else if (o < 49152)  prep_one(W4, Wf4, 64, o - 40960);
}

// ---------------------------------------------------------------------------
// MFMA GEMM (dual) with fused alpha epilogue. 32 rows/wave, 128 rows/block.
// All A fragments (8x f16x8) loaded up-front; Wf in two register halves.
// ---------------------------------------------------------------------------
template<int M, bool AHALF>
__global__ __launch_bounds__(256) void gemm_mfma_dual(
    const void* __restrict__ XA, const _Float16* __restrict__ WfA,
    const float* __restrict__ bA, _Float16* __restrict__ outA,
    const float* __restrict__ svA, const float* __restrict__ dvA,
    float* __restrict__ asA, float* __restrict__ adA,
    const void* __restrict__ XB, const _Float16* __restrict__ WfB,
    const float* __restrict__ bB, _Float16* __restrict__ outB,
    const float* __restrict__ svB, const float* __restrict__ dvB,
    float* __restrict__ asB, float* __restrict__ adB,
    int N, int nbHalf) {
    constexpr int NT = M / 16;
    constexpr int D  = M / HEADS;
    __shared__ _Float16 stage[4][32][M + 4];

    const bool second = blockIdx.x >= nbHalf;
    const void* __restrict__ X      = second ? XB : XA;
    const _Float16* __restrict__ Wf = second ? WfB : WfA;
    const float* __restrict__ b     = second ? bB : bA;
    _Float16* __restrict__ out      = second ? outB : outA;
    const float* __restrict__ sv    = second ? svB : svA;
    const float* __restrict__ dv    = second ? dvB : dvA;
    float* __restrict__ asb         = second ? asB : asA;
    float* __restrict__ adb         = second ? adB : adA;
    const int brow = second ? blockIdx.x - nbHalf : blockIdx.x;

    const int wave = threadIdx.x >> 6;
    const int lane = threadIdx.x & 63;
    const int row0 = (brow * 4 + wave) * 32;
    const int m    = lane & 15;
    const int quad = lane >> 4;

    int ar[2];
    ar[0] = row0 + m;       if (ar[0] >= N) ar[0] = N - 1;
    ar[1] = row0 + 16 + m;  if (ar[1] >= N) ar[1] = N - 1;

    // --- all A fragments up-front: 8 (or 16 fp32) independent global loads
    f16x8 areg[2][4];
    #pragma unroll
    for (int t = 0; t < 4; ++t) {
        const int k0 = t * 32 + quad * 8;
        #pragma unroll
        for (int f = 0; f < 2; ++f) {
            if (AHALF) {
                areg[f][t] = *(const f16x8*)((const _Float16*)X + (size_t)ar[f] * 128 + k0);
            } else {
                const float* xp = (const float*)X + (size_t)ar[f] * 128 + k0;
                float4 v0 = *(const float4*)xp;
                float4 v1 = *(const float4*)(xp + 4);
                areg[f][t] = (f16x8){(_Float16)v0.x, (_Float16)v0.y, (_Float16)v0.z, (_Float16)v0.w,
                                     (_Float16)v1.x, (_Float16)v1.y, (_Float16)v1.z, (_Float16)v1.w};
            }
        }
    }

    f32x4 acc[2][NT];
    #pragma unroll
    for (int f = 0; f < 2; ++f)
        #pragma unroll
        for (int j = 0; j < NT; ++j) acc[f][j] = (f32x4){0.f, 0.f, 0.f, 0.f};

    // --- MFMA in two t-halves; Wf half held in registers (NT*2 x f16x8)
    #pragma unroll
    for (int th = 0; th < 2; ++th) {
        f16x8 wreg[2][NT];
        #pragma unroll
        for (int tt = 0; tt < 2; ++tt)
            #pragma unroll
            for (int j = 0; j < NT; ++j)
                wreg[tt][j] = *(const f16x8*)(Wf + ((size_t)((th * 2 + tt) * NT + j) * 64 + lane) * 8);
        #pragma unroll
        for (int tt = 0; tt < 2; ++tt)
            #pragma unroll
            for (int f = 0; f < 2; ++f)
                #pragma unroll
                for (int j = 0; j < NT; ++j)
                    acc[f][j] = __builtin_amdgcn_mfma_f32_16x16x32_f16(
                        areg[f][th * 2 + tt], wreg[tt][j], acc[f][j], 0, 0, 0);
    }

    // C/D: col = lane&15, row = quad*4 + reg  (stage is wave-private)
    #pragma unroll
    for (int f = 0; f < 2; ++f)
        #pragma unroll
        for (int j = 0; j < NT; ++j) {
            const float bias = b[j * 16 + m];
            #pragma unroll
            for (int r = 0; r < 4; ++r)
                stage[wave][f * 16 + quad * 4 + r][j * 16 + m] = (_Float16)(acc[f][j][r] + bias);
        }

    // fused alpha: lane -> (row r, head hh), two 16-row groups
    #pragma unroll
    for (int f = 0; f < 2; ++f) {
        const int r  = f * 16 + (lane >> 2);
        const int hh = lane & 3;
        float ps = 0.f, pd = 0.f;
        #pragma unroll
        for (int j = 0; j < D / 4; ++j) {
            f16x4 v4 = *(const f16x4*)(&stage[wave][r][hh * D + 4 * j]);
            float4 s4 = *(const float4*)(sv + hh * D + 4 * j);
            float4 d4 = *(const float4*)(dv + hh * D + 4 * j);
            const float v0 = (float)v4[0], v1 = (float)v4[1],
                        v2 = (float)v4[2], v3 = (float)v4[3];
            ps += v0 * s4.x + v1 * s4.y + v2 * s4.z + v3 * s4.w;
            pd += v0 * d4.x + v1 * d4.y + v2 * d4.z + v3 * d4.w;
        }
        const int grow = row0 + r;
        if (grow < N) {
            asb[(size_t)grow * HEADS + hh] = ps;
            adb[(size_t)grow * HEADS + hh] = pd;
        }
    }

    // coalesced fp16 store
    constexpr int LPR = M / 4;
    constexpr int RPI = 64 / LPR;
    const int lr = lane % LPR;
    const int rq = lane / LPR;
    #pragma unroll
    for (int i = 0; i < 32 / RPI; ++i) {
        const int rr = i * RPI + rq;
        const int grow = row0 + rr;
        if (grow < N) {
            f16x4 v = *(const f16x4*)(&stage[wave][rr][lr * 4]);
            *(f16x4*)(out + (size_t)grow * M + lr * 4) = v;
        }
    }
}

// ---------------------------------------------------------------------------
// CSR build over the CONCATENATED 2N segment space.
// ---------------------------------------------------------------------------
__global__ __launch_bounds__(256) void hist_dual(
    const int* __restrict__ dst_pa, const int* __restrict__ dst_ap,
    int* __restrict__ counts, int N, int E) {
    const int eg = blockIdx.x * 256 + threadIdx.x;
    if (eg >= 2 * E) return;
    const int idx = (eg < E) ? dst_pa[eg] : (N + dst_ap[eg - E]);
    atomicAdd(counts + idx, 1);
}

__global__ __launch_bounds__(256) void scan_blk(
    const int* __restrict__ in, int* __restrict__ out,
    int* __restrict__ bsum, int N) {
    __shared__ int sh[256];
    const int base = blockIdx.x * 1024 + threadIdx.x * 4;
    int v[4]; int s = 0;
    #pragma unroll
    for (int j = 0; j < 4; ++j) { v[j] = (base + j < N) ? in[base + j] : 0; s += v[j]; }
    sh[threadIdx.x] = s;
    __syncthreads();
    for (int off = 1; off < 256; off <<= 1) {
        int t = (threadIdx.x >= off) ? sh[threadIdx.x - off] : 0;
        __syncthreads();
        sh[threadIdx.x] += t;
        __syncthreads();
    }
    int run = sh[threadIdx.x] - s;
    #pragma unroll
    for (int j = 0; j < 4; ++j) {
        if (base + j < N) out[base + j] = run;
        run += v[j];
    }
    if (threadIdx.x == 255) bsum[blockIdx.x] = sh[255];
}

__global__ __launch_bounds__(256) void scan_sums(int* __restrict__ bsum, int nb) {
    __shared__ int sh[256];
    int v = (threadIdx.x < nb) ? bsum[threadIdx.x] : 0;
    sh[threadIdx.x] = v;
    __syncthreads();
    for (int off = 1; off < 256; off <<= 1) {
        int t = (threadIdx.x >= off) ? sh[threadIdx.x - off] : 0;
        __syncthreads();
        sh[threadIdx.x] += t;
        __syncthreads();
    }
    if (threadIdx.x < nb) bsum[threadIdx.x] = sh[threadIdx.x] - v;
}

__global__ __launch_bounds__(256) void scan_add(
    int* __restrict__ out, const int* __restrict__ bsum, int N) {
    const int base = blockIdx.x * 1024 + threadIdx.x * 4;
    const int add = bsum[blockIdx.x];
    #pragma unroll
    for (int j = 0; j < 4; ++j)
        if (base + j < N) out[base + j] += add;
}

__global__ __launch_bounds__(256) void scatter_dual(
    const int* __restrict__ src_pa, const int* __restrict__ dst_pa,
    const int* __restrict__ src_ap, const int* __restrict__ dst_ap,
    const int* __restrict__ offsets, int* __restrict__ cursor,
    int* __restrict__ perm, int N, int E) {
    const int eg = blockIdx.x * 256 + threadIdx.x;
    if (eg >= 2 * E) return;
    int idx, val;
    if (eg < E) { idx = dst_pa[eg];         val = src_pa[eg]; }
    else        { idx = N + dst_ap[eg - E]; val = src_ap[eg - E]; }
    const int pos = offsets[idx] + atomicAdd(cursor + idx, 1);
    perm[pos] = val;
}

// ---------------------------------------------------------------------------
// Degree bucket sort of the 2N segments (64 buckets, clamped).
// ---------------------------------------------------------------------------
__global__ __launch_bounds__(256) void deg_hist(
    const int* __restrict__ cnt, int* __restrict__ bhist, int n) {
    __shared__ int lh[64];
    if (threadIdx.x < 64) lh[threadIdx.x] = 0;
    __syncthreads();
    for (int i = blockIdx.x * 256 + threadIdx.x; i < n; i += gridDim.x * 256) {
        int c = cnt[i]; if (c > 63) c = 63;
        atomicAdd(&lh[c], 1);
    }
    __syncthreads();
    if (threadIdx.x < 64) atomicAdd(&bhist[threadIdx.x], lh[threadIdx.x]);
}

__global__ __launch_bounds__(256) void deg_scatter(
    const int* __restrict__ cnt, int* __restrict__ bcur,
    int* __restrict__ order, int n) {
    __shared__ int lh[64];
    __shared__ int lbase[64];
    if (threadIdx.x < 64) lh[threadIdx.x] = 0;
    __syncthreads();
    const int i = blockIdx.x * 256 + threadIdx.x;
    int c = 0, lpos = 0;
    if (i < n) {
        c = cnt[i]; if (c > 63) c = 63;
        lpos = atomicAdd(&lh[c], 1);
    }
    __syncthreads();
    if (threadIdx.x < 64 && lh[threadIdx.x] > 0)
        lbase[threadIdx.x] = atomicAdd(&bcur[threadIdx.x], lh[threadIdx.x]);
    __syncthreads();
    if (i < n) order[lbase[c] + lpos] = i;
}

// ---------------------------------------------------------------------------
// Fused single-pass per-dst softmax + aggregation, degree-ordered,
// 4x-unrolled inner loop (4 independent gather chains in flight).
// ---------------------------------------------------------------------------
template<int F, int D>
__global__ __launch_bounds__(256) void csr_attn_agg_dual(
    const int* __restrict__ order,
    const int* __restrict__ perm, const int* __restrict__ offsets,
    const int* __restrict__ counts,
    const float* __restrict__ asrcP, const float* __restrict__ adstP,
    const _Float16* __restrict__ hP, _Float16* __restrict__ outA,
    const float* __restrict__ asrcA, const float* __restrict__ adstA,
    const _Float16* __restrict__ hA, _Float16* __restrict__ outP,
    int N) {
    constexpr int LPN = F / 4;
    const int gid  = blockIdx.x * 256 + threadIdx.x;
    const int slot = gid / LPN;
    const int lane = gid % LPN;
    if (slot >= 2 * N) return;
    const int node_g = order[slot];
    const bool second = node_g >= N;
    const int node = second ? node_g - N : node_g;
    const float* __restrict__ asrc    = second ? asrcA : asrcP;
    const float* __restrict__ adst    = second ? adstA : adstP;
    const _Float16* __restrict__ hsrc = second ? hA : hP;
    _Float16* __restrict__ out        = second ? outP : outA;

    const int start = offsets[node_g];
    const int cnt   = counts[node_g];
    const int f0 = lane * 4;
    const int h  = f0 / D;
    const float ad = adst[(size_t)node * HEADS + h];

    float den = 0.f;
    float4 acc = make_float4(0.f, 0.f, 0.f, 0.f);
    int i = 0;
    for (; i + 4 <= cnt; i += 4) {
        const int s0 = perm[start + i + 0];
        const int s1 = perm[start + i + 1];
        const int s2 = perm[start + i + 2];
        const int s3 = perm[start + i + 3];
        const float a0 = asrc[(size_t)s0 * HEADS + h];
        const float a1 = asrc[(size_t)s1 * HEADS + h];
        const float a2 = asrc[(size_t)s2 * HEADS + h];
        const float a3 = asrc[(size_t)s3 * HEADS + h];
        f16x4 h0 = *(const f16x4*)(hsrc + (size_t)s0 * F + f0);
        f16x4 h1 = *(const f16x4*)(hsrc + (size_t)s1 * F + f0);
        f16x4 h2 = *(const f16x4*)(hsrc + (size_t)s2 * F + f0);
        f16x4 h3 = *(const f16x4*)(hsrc + (size_t)s3 * F + f0);
        const float e0 = __expf(leaky02(a0 + ad));
        const float e1 = __expf(leaky02(a1 + ad));
        const float e2 = __expf(leaky02(a2 + ad));
        const float e3 = __expf(leaky02(a3 + ad));
        den += (e0 + e1) + (e2 + e3);
        acc.x += e0 * (float)h0[0] + e1 * (float)h1[0] + e2 * (float)h2[0] + e3 * (float)h3[0];
        acc.y += e0 * (float)h0[1] + e1 * (float)h1[1] + e2 * (float)h2[1] + e3 * (float)h3[1];
        acc.z += e0 * (float)h0[2] + e1 * (float)h1[2] + e2 * (float)h2[2] + e3 * (float)h3[2];
        acc.w += e0 * (float)h0[3] + e1 * (float)h1[3] + e2 * (float)h2[3] + e3 * (float)h3[3];
    }
    for (; i < cnt; ++i) {
        const int s = perm[start + i];
        const float a = leaky02(asrc[(size_t)s * HEADS + h] + ad);
        const float ex = __expf(a);
        den += ex;
        f16x4 hv = *(const f16x4*)(hsrc + (size_t)s * F + f0);
        acc.x += ex * (float)hv[0]; acc.y += ex * (float)hv[1];
        acc.z += ex * (float)hv[2]; acc.w += ex * (float)hv[3];
    }
    const float inv = 1.f / (den + 1e-16f);
    f16x4 o;
    o[0] = (_Float16)fmaxf(acc.x * inv, 0.f);
    o[1] = (_Float16)fmaxf(acc.y * inv, 0.f);
    o[2] = (_Float16)fmaxf(acc.z * inv, 0.f);
    o[3] = (_Float16)fmaxf(acc.w * inv, 0.f);
    *(f16x4*)(out + (size_t)node * F + f0) = o;
}

// ---------------------------------------------------------------------------
// Final: out[l] = dot(zp[eli0[l]], za[eli1[l]]), 64 fp16 feats -> fp32.
// ---------------------------------------------------------------------------
__global__ __launch_bounds__(256) void edge_dot(
    const int* __restrict__ eli, const _Float16* __restrict__ zp,
    const _Float16* __restrict__ za, float* __restrict__ out, int L) {
    constexpr int LPE = 16;
    const int gid  = blockIdx.x * blockDim.x + threadIdx.x;
    const int e    = gid / LPE;
    const int lane = gid % LPE;
    if (e >= L) return;
    const int p = eli[e], a = eli[(size_t)L + e];
    f16x4 pv = *(const f16x4*)(zp + (size_t)p * 64 + lane * 4);
    f16x4 av = *(const f16x4*)(za + (size_t)a * 64 + lane * 4);
    float s = (float)pv[0] * (float)av[0] + (float)pv[1] * (float)av[1]
            + (float)pv[2] * (float)av[2] + (float)pv[3] * (float)av[3];
    #pragma unroll
    for (int off = 8; off > 0; off >>= 1) s += __shfl_xor(s, off);
    if (lane == 0) out[e] = s;
}

// ---------------------------------------------------------------------------
static inline int cdiv(long long a, long long b) { return (int)((a + b - 1) / b); }

extern "C" void kernel_launch(void* const* d_in, const int* in_sizes, int n_in,
                              void* d_out, int out_size, void* d_ws, size_t ws_size,
                              hipStream_t stream) {
    const float* x_p  = (const float*)d_in[0];
    const float* x_a  = (const float*)d_in[1];
    const int* ei_pa  = (const int*)d_in[2];
    const int* ei_ap  = (const int*)d_in[3];
    const int* eli    = (const int*)d_in[4];
    const float* p1W = (const float*)d_in[5];
    const float* p1b = (const float*)d_in[6];
    const float* a1W = (const float*)d_in[7];
    const float* a1b = (const float*)d_in[8];
    const float* s1pa = (const float*)d_in[9];
    const float* d1pa = (const float*)d_in[10];
    const float* s1ap = (const float*)d_in[11];
    const float* d1ap = (const float*)d_in[12];
    // 13..15: k1W, k1b, q1 — dead (single-metapath group == identity)
    const float* p2W = (const float*)d_in[16];
    const float* p2b = (const float*)d_in[17];
    const float* a2W = (const float*)d_in[18];
    const float* a2b = (const float*)d_in[19];
    const float* s2pa = (const float*)d_in[20];
    const float* d2pa = (const float*)d_in[21];
    const float* s2ap = (const float*)d_in[22];
    const float* d2ap = (const float*)d_in[23];
    // 24..26: k2W, k2b, q2 — dead

    const int NP = in_sizes[0] / 128;
    const int E  = in_sizes[2] / 2;
    const int L  = in_sizes[4] / 2;
    const int N  = NP;  // NP == NA

    // ---- workspace layout ----
    char* ws = (char*)d_ws;
    size_t off = 0;
    auto alloc = [&](size_t bytes) -> char* {
        char* p = ws + off;
        off += (bytes + 255) & ~(size_t)255;
        return p;
    };
    _Float16* h_p1   = (_Float16*)alloc((size_t)N * 128 * 2);
    _Float16* h_a1   = (_Float16*)alloc((size_t)N * 128 * 2);
    _Float16* out_p1 = (_Float16*)alloc((size_t)N * 128 * 2);
    _Float16* out_a1 = (_Float16*)alloc((size_t)N * 128 * 2);
    _Float16* h_p2   = (_Float16*)alloc((size_t)N * 64 * 2);
    _Float16* h_a2   = (_Float16*)alloc((size_t)N * 64 * 2);
    _Float16* out_p2 = (_Float16*)alloc((size_t)N * 64 * 2);
    _Float16* out_a2 = (_Float16*)alloc((size_t)N * 64 * 2);
    float* asrc_pa = (float*)alloc((size_t)N * HEADS * 4);
    float* adst_pa = (float*)alloc((size_t)N * HEADS * 4);
    float* asrc_ap = (float*)alloc((size_t)N * HEADS * 4);
    float* adst_ap = (float*)alloc((size_t)N * HEADS * 4);
    _Float16* Wf1p = (_Float16*)alloc(16384 * 2);
    _Float16* Wf1a = (_Float16*)alloc(16384 * 2);
    _Float16* Wf2p = (_Float16*)alloc(8192 * 2);
    _Float16* Wf2a = (_Float16*)alloc(8192 * 2);
    // cnt2 / cursor2 / bhist are contiguous: one memset covers them
    int* cnt2    = (int*)alloc((size_t)2 * N * 4);
    int* cursor2 = (int*)alloc((size_t)2 * N * 4);
    int* bhist   = (int*)alloc(256);            // 64 ints
    int* off2    = (int*)alloc((size_t)2 * N * 4);
    int* perm2   = (int*)alloc((size_t)2 * E * 4);
    int* order2  = (int*)alloc((size_t)2 * N * 4);
    int* bsum    = (int*)alloc(256 * 4);

    const int* src_pa = ei_pa;       // papers
    const int* dst_pa = ei_pa + E;   // authors
    const int* src_ap = ei_ap;       // authors
    const int* dst_ap = ei_ap + E;   // papers

    const int N2 = 2 * N;
    const int nbScan = cdiv(N2, 1024);

    // ================= prep + CSR build + degree sort =================
    prep_w4<<<cdiv(49152, 256), 256, 0, stream>>>(p1W, Wf1p, a1W, Wf1a, p2W, Wf2p, a2W, Wf2a);
    hipMemsetAsync(cnt2, 0, ((size_t)4 * N + 64) * 4, stream);  // cnt2+cursor2+bhist
    hist_dual<<<cdiv((long long)2 * E, 256), 256, 0, stream>>>(dst_pa, dst_ap, cnt2, N, E);
    scan_blk<<<nbScan, 256, 0, stream>>>(cnt2, off2, bsum, N2);
    scan_sums<<<1, 256, 0, stream>>>(bsum, nbScan);
    scan_add<<<nbScan, 256, 0, stream>>>(off2, bsum, N2);
    scatter_dual<<<cdiv((long long)2 * E, 256), 256, 0, stream>>>(
        src_pa, dst_pa, src_ap, dst_ap, off2, cursor2, perm2, N, E);
    deg_hist<<<256, 256, 0, stream>>>(cnt2, bhist, N2);
    scan_sums<<<1, 256, 0, stream>>>(bhist, 64);
    deg_scatter<<<cdiv(N2, 256), 256, 0, stream>>>(cnt2, bhist, order2, N2);

    const int nbHalf = cdiv(N, 128);

    // ================= Layer 1 =================
    gemm_mfma_dual<128, false><<<2 * nbHalf, 256, 0, stream>>>(
        x_p, Wf1p, p1b, h_p1, s1pa, d1ap, asrc_pa, adst_ap,
        x_a, Wf1a, a1b, h_a1, s1ap, d1pa, asrc_ap, adst_pa, N, nbHalf);
    csr_attn_agg_dual<128, 32><<<cdiv((long long)N2 * 32, 256), 256, 0, stream>>>(
        order2, perm2, off2, cnt2,
        asrc_pa, adst_pa, h_p1, out_a1,
        asrc_ap, adst_ap, h_a1, out_p1, N);

    // ================= Layer 2 =================
    gemm_mfma_dual<64, true><<<2 * nbHalf, 256, 0, stream>>>(
        out_p1, Wf2p, p2b, h_p2, s2pa, d2ap, asrc_pa, adst_ap,
        out_a1, Wf2a, a2b, h_a2, s2ap, d2pa, asrc_ap, adst_pa, N, nbHalf);
    csr_attn_agg_dual<64, 16><<<cdiv((long long)N2 * 16, 256), 256, 0, stream>>>(
        order2, perm2, off2, cnt2,
        asrc_pa, adst_pa, h_p2, out_a2,
        asrc_ap, adst_ap, h_a2, out_p2, N);

    // ================= Final dot =================
    edge_dot<<<cdiv((long long)L * 16, 256), 256, 0, stream>>>(
        eli, out_p2, out_a2, (float*)d_out, L);
}

// Round 9
// 454.730 us; speedup vs baseline: 1.0301x; 1.0301x over previous
//
#include <hip/hip_runtime.h>

// ---------------------------------------------------------------------------
// HAN link-prediction forward. fp16 MFMA GEMMs + fp16 intermediates,
// fp32 alpha tables / accumulation / output.
//   - _group with one metapath == identity (k*W/k*b/q* are dead params)
//   - concatenated 2N-segment CSR (one build serves both directions+layers)
//   - degree-bucketed node order; single-pass agg, 4x-unrolled gathers
//   - GEMM: ALL global loads coalesced; A tile staged+converted through
//     padded LDS (the R7/R8 register-direct A loads touched 16 cache lines
//     per instruction -> transaction-bound at 3% MfmaUtil); Wf block-copied
//     to LDS; fragments via ds_read_b128; fused alpha epilogue.
// ---------------------------------------------------------------------------

#define HEADS 4

typedef _Float16 f16x8 __attribute__((ext_vector_type(8)));
typedef _Float16 f16x4 __attribute__((ext_vector_type(4)));
typedef float    f32x4 __attribute__((ext_vector_type(4)));

__device__ __forceinline__ float leaky02(float a) {
    return a >= 0.f ? a : 0.2f * a;
}

// ---------------------------------------------------------------------------
// W prep: fp32 [K=128][M] row-major -> fp16 fragment-ordered
// ---------------------------------------------------------------------------
__device__ __forceinline__ void prep_one(const float* W, _Float16* Wf, int M, int o) {
    const int NT = M / 16;
    const int v = o & 7, lane = (o >> 3) & 63, jt = o >> 9;
    const int t = jt / NT, j = jt % NT;
    const int k = t * 32 + (lane >> 4) * 8 + v;
    const int n = j * 16 + (lane & 15);
    Wf[o] = (_Float16)W[k * M + n];
}

__global__ __launch_bounds__(256) void prep_w4(
    const float* __restrict__ W1, _Float16* __restrict__ Wf1,
    const float* __restrict__ W2, _Float16* __restrict__ Wf2,
    const float* __restrict__ W3, _Float16* __restrict__ Wf3,
    const float* __restrict__ W4, _Float16* __restrict__ Wf4) {
    int o = blockIdx.x * 256 + threadIdx.x;
    if (o < 16384)       prep_one(W1, Wf1, 128, o);
    else if (o < 32768)  prep_one(W2, Wf2, 128, o - 16384);
    else if (o < 40960)  prep_one(W3, Wf3, 64, o - 32768);
    else if (o < 49152)  prep_one(W4, Wf4, 64, o - 40960);
}

// ---------------------------------------------------------------------------
// MFMA GEMM (dual) with fused alpha epilogue. 64 rows/block, 16 rows/wave.
// A tile: coalesced global load -> (cvt) -> padded LDS (stride 136 halfs).
// Wf: coalesced flat block copy -> LDS; fragments via ds_read_b128.
// Epilogue reuses the A LDS region (stride M+4) after a barrier.
// ---------------------------------------------------------------------------
template<int M, bool AHALF>
__global__ __launch_bounds__(256) void gemm_mfma_dual(
    const void* __restrict__ XA, const _Float16* __restrict__ WfA,
    const float* __restrict__ bA, _Float16* __restrict__ outA,
    const float* __restrict__ svA, const float* __restrict__ dvA,
    float* __restrict__ asA, float* __restrict__ adA,
    const void* __restrict__ XB, const _Float16* __restrict__ WfB,
    const float* __restrict__ bB, _Float16* __restrict__ outB,
    const float* __restrict__ svB, const float* __restrict__ dvB,
    float* __restrict__ asB, float* __restrict__ adB,
    int N, int nbHalf) {
    constexpr int NT  = M / 16;
    constexpr int D   = M / HEADS;
    constexpr int SA  = 136;                // A-stage stride (halfs): 272 B, 16B-aligned
    constexpr int SE  = M + 4;              // epilogue stride (halfs)
    constexpr int WFH = NT * 4 * 64 * 8;    // Wf halfs (M=128: 16384, M=64: 8192)
    __shared__ _Float16 lds_a[64 * SA];
    __shared__ _Float16 lds_w[WFH];

    const bool second = blockIdx.x >= nbHalf;
    const void* __restrict__ X      = second ? XB : XA;
    const _Float16* __restrict__ Wf = second ? WfB : WfA;
    const float* __restrict__ b     = second ? bB : bA;
    _Float16* __restrict__ out      = second ? outB : outA;
    const float* __restrict__ sv    = second ? svB : svA;
    const float* __restrict__ dv    = second ? dvB : dvA;
    float* __restrict__ asb         = second ? asB : asA;
    float* __restrict__ adb         = second ? adB : adA;
    const int brow = second ? blockIdx.x - nbHalf : blockIdx.x;

    const int wave = threadIdx.x >> 6;
    const int lane = threadIdx.x & 63;
    const int row0 = brow * 64;
    const int m    = lane & 15;
    const int quad = lane >> 4;

    // ---- stage Wf -> LDS (flat copy, fully coalesced f16x8)
    {
        const int base = threadIdx.x * 8;     // 2048 halfs per iter
        #pragma unroll
        for (int it = 0; it < WFH / 2048; ++it) {
            f16x8 v = *(const f16x8*)(Wf + it * 2048 + base);
            *(f16x8*)(lds_w + it * 2048 + base) = v;
        }
    }
    // ---- stage A -> LDS (coalesced rows, cvt fp32->fp16 if needed)
    if (AHALF) {
        #pragma unroll
        for (int it = 0; it < 4; ++it) {
            const int r = it * 16 + (threadIdx.x >> 4);
            const int k = (threadIdx.x & 15) * 8;
            int gr = row0 + r; if (gr >= N) gr = N - 1;
            f16x8 v = *(const f16x8*)((const _Float16*)X + (size_t)gr * 128 + k);
            *(f16x8*)(lds_a + r * SA + k) = v;
        }
    } else {
        #pragma unroll
        for (int it = 0; it < 8; ++it) {
            const int r = it * 8 + (threadIdx.x >> 5);
            const int k = (threadIdx.x & 31) * 4;
            int gr = row0 + r; if (gr >= N) gr = N - 1;
            float4 v = *(const float4*)((const float*)X + (size_t)gr * 128 + k);
            f16x4 h = {(_Float16)v.x, (_Float16)v.y, (_Float16)v.z, (_Float16)v.w};
            *(f16x4*)(lds_a + r * SA + k) = h;
        }
    }
    __syncthreads();

    f32x4 acc[NT];
    #pragma unroll
    for (int j = 0; j < NT; ++j) acc[j] = (f32x4){0.f, 0.f, 0.f, 0.f};

    const int ab = (wave * 16 + m) * SA;
    #pragma unroll
    for (int t = 0; t < 4; ++t) {
        f16x8 a = *(const f16x8*)(lds_a + ab + t * 32 + quad * 8);
        #pragma unroll
        for (int j = 0; j < NT; ++j) {
            f16x8 bf = *(const f16x8*)(lds_w + ((t * NT + j) * 64 + lane) * 8);
            acc[j] = __builtin_amdgcn_mfma_f32_16x16x32_f16(a, bf, acc[j], 0, 0, 0);
        }
    }
    __syncthreads();   // all A reads done before epilogue overwrites lds_a

    // C/D: col = lane&15, row = quad*4 + reg -> LDS at stride SE (wave-private rows)
    #pragma unroll
    for (int j = 0; j < NT; ++j) {
        const float bias = b[j * 16 + m];
        #pragma unroll
        for (int r = 0; r < 4; ++r)
            lds_a[(wave * 16 + quad * 4 + r) * SE + j * 16 + m] =
                (_Float16)(acc[j][r] + bias);
    }

    // fused alpha: lane -> (row r, head hh)
    {
        const int r  = lane >> 2;
        const int hh = lane & 3;
        float ps = 0.f, pd = 0.f;
        #pragma unroll
        for (int j = 0; j < D / 4; ++j) {
            f16x4 v4 = *(const f16x4*)(&lds_a[(wave * 16 + r) * SE + hh * D + 4 * j]);
            float4 s4 = *(const float4*)(sv + hh * D + 4 * j);
            float4 d4 = *(const float4*)(dv + hh * D + 4 * j);
            const float v0 = (float)v4[0], v1 = (float)v4[1],
                        v2 = (float)v4[2], v3 = (float)v4[3];
            ps += v0 * s4.x + v1 * s4.y + v2 * s4.z + v3 * s4.w;
            pd += v0 * d4.x + v1 * d4.y + v2 * d4.z + v3 * d4.w;
        }
        const int grow = row0 + wave * 16 + r;
        if (grow < N) {
            asb[(size_t)grow * HEADS + hh] = ps;
            adb[(size_t)grow * HEADS + hh] = pd;
        }
    }

    // coalesced fp16 store of this wave's 16 rows
    constexpr int LPR = M / 4;
    constexpr int RPI = 64 / LPR;
    const int lr = lane % LPR;
    const int rq = lane / LPR;
    #pragma unroll
    for (int i = 0; i < 16 / RPI; ++i) {
        const int rr = wave * 16 + i * RPI + rq;
        const int grow = row0 + rr;
        if (grow < N) {
            f16x4 v = *(const f16x4*)(&lds_a[rr * SE + lr * 4]);
            *(f16x4*)(out + (size_t)grow * M + lr * 4) = v;
        }
    }
}

// ---------------------------------------------------------------------------
// CSR build over the CONCATENATED 2N segment space.
// ---------------------------------------------------------------------------
__global__ __launch_bounds__(256) void hist_dual(
    const int* __restrict__ dst_pa, const int* __restrict__ dst_ap,
    int* __restrict__ counts, int N, int E) {
    const int eg = blockIdx.x * 256 + threadIdx.x;
    if (eg >= 2 * E) return;
    const int idx = (eg < E) ? dst_pa[eg] : (N + dst_ap[eg - E]);
    atomicAdd(counts + idx, 1);
}

__global__ __launch_bounds__(256) void scan_blk(
    const int* __restrict__ in, int* __restrict__ out,
    int* __restrict__ bsum, int N) {
    __shared__ int sh[256];
    const int base = blockIdx.x * 1024 + threadIdx.x * 4;
    int v[4]; int s = 0;
    #pragma unroll
    for (int j = 0; j < 4; ++j) { v[j] = (base + j < N) ? in[base + j] : 0; s += v[j]; }
    sh[threadIdx.x] = s;
    __syncthreads();
    for (int off = 1; off < 256; off <<= 1) {
        int t = (threadIdx.x >= off) ? sh[threadIdx.x - off] : 0;
        __syncthreads();
        sh[threadIdx.x] += t;
        __syncthreads();
    }
    int run = sh[threadIdx.x] - s;
    #pragma unroll
    for (int j = 0; j < 4; ++j) {
        if (base + j < N) out[base + j] = run;
        run += v[j];
    }
    if (threadIdx.x == 255) bsum[blockIdx.x] = sh[255];
}

__global__ __launch_bounds__(256) void scan_sums(int* __restrict__ bsum, int nb) {
    __shared__ int sh[256];
    int v = (threadIdx.x < nb) ? bsum[threadIdx.x] : 0;
    sh[threadIdx.x] = v;
    __syncthreads();
    for (int off = 1; off < 256; off <<= 1) {
        int t = (threadIdx.x >= off) ? sh[threadIdx.x - off] : 0;
        __syncthreads();
        sh[threadIdx.x] += t;
        __syncthreads();
    }
    if (threadIdx.x < nb) bsum[threadIdx.x] = sh[threadIdx.x] - v;
}

__global__ __launch_bounds__(256) void scan_add(
    int* __restrict__ out, const int* __restrict__ bsum, int N) {
    const int base = blockIdx.x * 1024 + threadIdx.x * 4;
    const int add = bsum[blockIdx.x];
    #pragma unroll
    for (int j = 0; j < 4; ++j)
        if (base + j < N) out[base + j] += add;
}

__global__ __launch_bounds__(256) void scatter_dual(
    const int* __restrict__ src_pa, const int* __restrict__ dst_pa,
    const int* __restrict__ src_ap, const int* __restrict__ dst_ap,
    const int* __restrict__ offsets, int* __restrict__ cursor,
    int* __restrict__ perm, int N, int E) {
    const int eg = blockIdx.x * 256 + threadIdx.x;
    if (eg >= 2 * E) return;
    int idx, val;
    if (eg < E) { idx = dst_pa[eg];         val = src_pa[eg]; }
    else        { idx = N + dst_ap[eg - E]; val = src_ap[eg - E]; }
    const int pos = offsets[idx] + atomicAdd(cursor + idx, 1);
    perm[pos] = val;
}

// ---------------------------------------------------------------------------
// Degree bucket sort of the 2N segments (64 buckets, clamped).
// ---------------------------------------------------------------------------
__global__ __launch_bounds__(256) void deg_hist(
    const int* __restrict__ cnt, int* __restrict__ bhist, int n) {
    __shared__ int lh[64];
    if (threadIdx.x < 64) lh[threadIdx.x] = 0;
    __syncthreads();
    for (int i = blockIdx.x * 256 + threadIdx.x; i < n; i += gridDim.x * 256) {
        int c = cnt[i]; if (c > 63) c = 63;
        atomicAdd(&lh[c], 1);
    }
    __syncthreads();
    if (threadIdx.x < 64) atomicAdd(&bhist[threadIdx.x], lh[threadIdx.x]);
}

__global__ __launch_bounds__(256) void deg_scatter(
    const int* __restrict__ cnt, int* __restrict__ bcur,
    int* __restrict__ order, int n) {
    __shared__ int lh[64];
    __shared__ int lbase[64];
    if (threadIdx.x < 64) lh[threadIdx.x] = 0;
    __syncthreads();
    const int i = blockIdx.x * 256 + threadIdx.x;
    int c = 0, lpos = 0;
    if (i < n) {
        c = cnt[i]; if (c > 63) c = 63;
        lpos = atomicAdd(&lh[c], 1);
    }
    __syncthreads();
    if (threadIdx.x < 64 && lh[threadIdx.x] > 0)
        lbase[threadIdx.x] = atomicAdd(&bcur[threadIdx.x], lh[threadIdx.x]);
    __syncthreads();
    if (i < n) order[lbase[c] + lpos] = i;
}

// ---------------------------------------------------------------------------
// Fused single-pass per-dst softmax + aggregation, degree-ordered,
// 4x-unrolled inner loop (4 independent gather chains in flight).
// ---------------------------------------------------------------------------
template<int F, int D>
__global__ __launch_bounds__(256) void csr_attn_agg_dual(
    const int* __restrict__ order,
    const int* __restrict__ perm, const int* __restrict__ offsets,
    const int* __restrict__ counts,
    const float* __restrict__ asrcP, const float* __restrict__ adstP,
    const _Float16* __restrict__ hP, _Float16* __restrict__ outA,
    const float* __restrict__ asrcA, const float* __restrict__ adstA,
    const _Float16* __restrict__ hA, _Float16* __restrict__ outP,
    int N) {
    constexpr int LPN = F / 4;
    const int gid  = blockIdx.x * 256 + threadIdx.x;
    const int slot = gid / LPN;
    const int lane = gid % LPN;
    if (slot >= 2 * N) return;
    const int node_g = order[slot];
    const bool second = node_g >= N;
    const int node = second ? node_g - N : node_g;
    const float* __restrict__ asrc    = second ? asrcA : asrcP;
    const float* __restrict__ adst    = second ? adstA : adstP;
    const _Float16* __restrict__ hsrc = second ? hA : hP;
    _Float16* __restrict__ out        = second ? outP : outA;

    const int start = offsets[node_g];
    const int cnt   = counts[node_g];
    const int f0 = lane * 4;
    const int h  = f0 / D;
    const float ad = adst[(size_t)node * HEADS + h];

    float den = 0.f;
    float4 acc = make_float4(0.f, 0.f, 0.f, 0.f);
    int i = 0;
    for (; i + 4 <= cnt; i += 4) {
        const int s0 = perm[start + i + 0];
        const int s1 = perm[start + i + 1];
        const int s2 = perm[start + i + 2];
        const int s3 = perm[start + i + 3];
        const float a0 = asrc[(size_t)s0 * HEADS + h];
        const float a1 = asrc[(size_t)s1 * HEADS + h];
        const float a2 = asrc[(size_t)s2 * HEADS + h];
        const float a3 = asrc[(size_t)s3 * HEADS + h];
        f16x4 h0 = *(const f16x4*)(hsrc + (size_t)s0 * F + f0);
        f16x4 h1 = *(const f16x4*)(hsrc + (size_t)s1 * F + f0);
        f16x4 h2 = *(const f16x4*)(hsrc + (size_t)s2 * F + f0);
        f16x4 h3 = *(const f16x4*)(hsrc + (size_t)s3 * F + f0);
        const float e0 = __expf(leaky02(a0 + ad));
        const float e1 = __expf(leaky02(a1 + ad));
        const float e2 = __expf(leaky02(a2 + ad));
        const float e3 = __expf(leaky02(a3 + ad));
        den += (e0 + e1) + (e2 + e3);
        acc.x += e0 * (float)h0[0] + e1 * (float)h1[0] + e2 * (float)h2[0] + e3 * (float)h3[0];
        acc.y += e0 * (float)h0[1] + e1 * (float)h1[1] + e2 * (float)h2[1] + e3 * (float)h3[1];
        acc.z += e0 * (float)h0[2] + e1 * (float)h1[2] + e2 * (float)h2[2] + e3 * (float)h3[2];
        acc.w += e0 * (float)h0[3] + e1 * (float)h1[3] + e2 * (float)h2[3] + e3 * (float)h3[3];
    }
    for (; i < cnt; ++i) {
        const int s = perm[start + i];
        const float a = leaky02(asrc[(size_t)s * HEADS + h] + ad);
        const float ex = __expf(a);
        den += ex;
        f16x4 hv = *(const f16x4*)(hsrc + (size_t)s * F + f0);
        acc.x += ex * (float)hv[0]; acc.y += ex * (float)hv[1];
        acc.z += ex * (float)hv[2]; acc.w += ex * (float)hv[3];
    }
    const float inv = 1.f / (den + 1e-16f);
    f16x4 o;
    o[0] = (_Float16)fmaxf(acc.x * inv, 0.f);
    o[1] = (_Float16)fmaxf(acc.y * inv, 0.f);
    o[2] = (_Float16)fmaxf(acc.z * inv, 0.f);
    o[3] = (_Float16)fmaxf(acc.w * inv, 0.f);
    *(f16x4*)(out + (size_t)node * F + f0) = o;
}

// ---------------------------------------------------------------------------
// Final: out[l] = dot(zp[eli0[l]], za[eli1[l]]), 64 fp16 feats -> fp32.
// ---------------------------------------------------------------------------
__global__ __launch_bounds__(256) void edge_dot(
    const int* __restrict__ eli, const _Float16* __restrict__ zp,
    const _Float16* __restrict__ za, float* __restrict__ out, int L) {
    constexpr int LPE = 16;
    const int gid  = blockIdx.x * blockDim.x + threadIdx.x;
    const int e    = gid / LPE;
    const int lane = gid % LPE;
    if (e >= L) return;
    const int p = eli[e], a = eli[(size_t)L + e];
    f16x4 pv = *(const f16x4*)(zp + (size_t)p * 64 + lane * 4);
    f16x4 av = *(const f16x4*)(za + (size_t)a * 64 + lane * 4);
    float s = (float)pv[0] * (float)av[0] + (float)pv[1] * (float)av[1]
            + (float)pv[2] * (float)av[2] + (float)pv[3] * (float)av[3];
    #pragma unroll
    for (int off = 8; off > 0; off >>= 1) s += __shfl_xor(s, off);
    if (lane == 0) out[e] = s;
}

// ---------------------------------------------------------------------------
static inline int cdiv(long long a, long long b) { return (int)((a + b - 1) / b); }

extern "C" void kernel_launch(void* const* d_in, const int* in_sizes, int n_in,
                              void* d_out, int out_size, void* d_ws, size_t ws_size,
                              hipStream_t stream) {
    const float* x_p  = (const float*)d_in[0];
    const float* x_a  = (const float*)d_in[1];
    const int* ei_pa  = (const int*)d_in[2];
    const int* ei_ap  = (const int*)d_in[3];
    const int* eli    = (const int*)d_in[4];
    const float* p1W = (const float*)d_in[5];
    const float* p1b = (const float*)d_in[6];
    const float* a1W = (const float*)d_in[7];
    const float* a1b = (const float*)d_in[8];
    const float* s1pa = (const float*)d_in[9];
    const float* d1pa = (const float*)d_in[10];
    const float* s1ap = (const float*)d_in[11];
    const float* d1ap = (const float*)d_in[12];
    // 13..15: k1W, k1b, q1 — dead (single-metapath group == identity)
    const float* p2W = (const float*)d_in[16];
    const float* p2b = (const float*)d_in[17];
    const float* a2W = (const float*)d_in[18];
    const float* a2b = (const float*)d_in[19];
    const float* s2pa = (const float*)d_in[20];
    const float* d2pa = (const float*)d_in[21];
    const float* s2ap = (const float*)d_in[22];
    const float* d2ap = (const float*)d_in[23];
    // 24..26: k2W, k2b, q2 — dead

    const int NP = in_sizes[0] / 128;
    const int E  = in_sizes[2] / 2;
    const int L  = in_sizes[4] / 2;
    const int N  = NP;  // NP == NA

    // ---- workspace layout ----
    char* ws = (char*)d_ws;
    size_t off = 0;
    auto alloc = [&](size_t bytes) -> char* {
        char* p = ws + off;
        off += (bytes + 255) & ~(size_t)255;
        return p;
    };
    _Float16* h_p1   = (_Float16*)alloc((size_t)N * 128 * 2);
    _Float16* h_a1   = (_Float16*)alloc((size_t)N * 128 * 2);
    _Float16* out_p1 = (_Float16*)alloc((size_t)N * 128 * 2);
    _Float16* out_a1 = (_Float16*)alloc((size_t)N * 128 * 2);
    _Float16* h_p2   = (_Float16*)alloc((size_t)N * 64 * 2);
    _Float16* h_a2   = (_Float16*)alloc((size_t)N * 64 * 2);
    _Float16* out_p2 = (_Float16*)alloc((size_t)N * 64 * 2);
    _Float16* out_a2 = (_Float16*)alloc((size_t)N * 64 * 2);
    float* asrc_pa = (float*)alloc((size_t)N * HEADS * 4);
    float* adst_pa = (float*)alloc((size_t)N * HEADS * 4);
    float* asrc_ap = (float*)alloc((size_t)N * HEADS * 4);
    float* adst_ap = (float*)alloc((size_t)N * HEADS * 4);
    _Float16* Wf1p = (_Float16*)alloc(16384 * 2);
    _Float16* Wf1a = (_Float16*)alloc(16384 * 2);
    _Float16* Wf2p = (_Float16*)alloc(8192 * 2);
    _Float16* Wf2a = (_Float16*)alloc(8192 * 2);
    // cnt2 / cursor2 / bhist are contiguous: one memset covers them
    int* cnt2    = (int*)alloc((size_t)2 * N * 4);
    int* cursor2 = (int*)alloc((size_t)2 * N * 4);
    int* bhist   = (int*)alloc(256);            // 64 ints
    int* off2    = (int*)alloc((size_t)2 * N * 4);
    int* perm2   = (int*)alloc((size_t)2 * E * 4);
    int* order2  = (int*)alloc((size_t)2 * N * 4);
    int* bsum    = (int*)alloc(256 * 4);

    const int* src_pa = ei_pa;       // papers
    const int* dst_pa = ei_pa + E;   // authors
    const int* src_ap = ei_ap;       // authors
    const int* dst_ap = ei_ap + E;   // papers

    const int N2 = 2 * N;
    const int nbScan = cdiv(N2, 1024);

    // ================= prep + CSR build + degree sort =================
    prep_w4<<<cdiv(49152, 256), 256, 0, stream>>>(p1W, Wf1p, a1W, Wf1a, p2W, Wf2p, a2W, Wf2a);
    hipMemsetAsync(cnt2, 0, ((size_t)4 * N + 64) * 4, stream);  // cnt2+cursor2+bhist
    hist_dual<<<cdiv((long long)2 * E, 256), 256, 0, stream>>>(dst_pa, dst_ap, cnt2, N, E);
    scan_blk<<<nbScan, 256, 0, stream>>>(cnt2, off2, bsum, N2);
    scan_sums<<<1, 256, 0, stream>>>(bsum, nbScan);
    scan_add<<<nbScan, 256, 0, stream>>>(off2, bsum, N2);
    scatter_dual<<<cdiv((long long)2 * E, 256), 256, 0, stream>>>(
        src_pa, dst_pa, src_ap, dst_ap, off2, cursor2, perm2, N, E);
    deg_hist<<<256, 256, 0, stream>>>(cnt2, bhist, N2);
    scan_sums<<<1, 256, 0, stream>>>(bhist, 64);
    deg_scatter<<<cdiv(N2, 256), 256, 0, stream>>>(cnt2, bhist, order2, N2);

    const int nbHalf = cdiv(N, 64);

    // ================= Layer 1 =================
    gemm_mfma_dual<128, false><<<2 * nbHalf, 256, 0, stream>>>(
        x_p, Wf1p, p1b, h_p1, s1pa, d1ap, asrc_pa, adst_ap,
        x_a, Wf1a, a1b, h_a1, s1ap, d1pa, asrc_ap, adst_pa, N, nbHalf);
    csr_attn_agg_dual<128, 32><<<cdiv((long long)N2 * 32, 256), 256, 0, stream>>>(
        order2, perm2, off2, cnt2,
        asrc_pa, adst_pa, h_p1, out_a1,
        asrc_ap, adst_ap, h_a1, out_p1, N);

    // ================= Layer 2 =================
    gemm_mfma_dual<64, true><<<2 * nbHalf, 256, 0, stream>>>(
        out_p1, Wf2p, p2b, h_p2, s2pa, d2ap, asrc_pa, adst_ap,
        out_a1, Wf2a, a2b, h_a2, s2ap, d2pa, asrc_ap, adst_pa, N, nbHalf);
    csr_attn_agg_dual<64, 16><<<cdiv((long long)N2 * 16, 256), 256, 0, stream>>>(
        order2, perm2, off2, cnt2,
        asrc_pa, adst_pa, h_p2, out_a2,
        asrc_ap, adst_ap, h_a2, out_p2, N);

    // ================= Final dot =================
    edge_dot<<<cdiv((long long)L * 16, 256), 256, 0, stream>>>(
        eli, out_p2, out_a2, (float*)d_out, L);
}